// Round 6
// baseline (93.931 us; speedup 1.0000x reference)
//
#include <hip/hip_runtime.h>
#include <math.h>

#define B_TOTAL 2048
#define I_TOTAL 2048
#define O_TOTAL 2048
#define KW 64
#define NIN 6
#define BLOCK 256

typedef __attribute__((ext_vector_type(2))) float f2;

// ws layout:
//   wp2 [O][32] f2 {base=sig(t[2j]), diff=sig(t[2j+1])-sig(t[2j])}  512 KB
//   m8  [O][8]  int32 (6 used, padded for aligned s_load)            64 KB
//   xT  [I][B]  x transposed                                         16 MB
#define WS_WP2 0
#define WS_M8  (512 * 1024)
#define WS_XT  (1024 * 1024)

// K1: 2048x2048 fp32 transpose (x -> xT) with prep fused in.
__global__ __launch_bounds__(BLOCK) void xpose_prep(
    const float* __restrict__ x,
    const float* __restrict__ table,
    const unsigned int* __restrict__ map_raw,
    float* __restrict__ xT,
    f2* __restrict__ wp2,
    int* __restrict__ m8)
{
    __shared__ float tile[64][65];
    const int t  = threadIdx.x;
    const int r0 = blockIdx.y * 64;
    const int c0 = blockIdx.x * 64;
    const int rr = t >> 4;            // 0..15
    const int cc = (t & 15) << 2;     // 0,4,...,60
    #pragma unroll
    for (int p = 0; p < 4; ++p) {
        int r = p * 16 + rr;
        float4 v = *(const float4*)(x + (size_t)(r0 + r) * I_TOTAL + c0 + cc);
        tile[r][cc + 0] = v.x; tile[r][cc + 1] = v.y;
        tile[r][cc + 2] = v.z; tile[r][cc + 3] = v.w;
    }

    // prep tail: pair-leaf weights (first 256 blocks) + mapping (first 48)
    const int bid = blockIdx.y * gridDim.x + blockIdx.x;   // 0..1023
    const int gid = bid * BLOCK + t;
    if (gid < O_TOTAL * 32) {
        int o = gid >> 5, j = gid & 31;
        float s0 = 1.0f / (1.0f + __expf(-table[o * KW + 2 * j]));
        float s1 = 1.0f / (1.0f + __expf(-table[o * KW + 2 * j + 1]));
        f2 v; v.x = s0; v.y = s1 - s0;
        wp2[gid] = v;
    }
    if (gid < O_TOTAL * NIN) {
        // int64 little-endian, values < 2048 => odd u32 words all zero.
        bool is64 = ((map_raw[1] | map_raw[3] | map_raw[5] | map_raw[7]) == 0u);
        int val = is64 ? (int)map_raw[2 * gid] : (int)map_raw[gid];
        int o = gid / NIN, i = gid - o * NIN;
        m8[o * 8 + i] = val;
    }

    __syncthreads();
    #pragma unroll
    for (int p = 0; p < 4; ++p) {
        int r = p * 16 + rr;          // row of dst tile = col of src tile
        float4 v;
        v.x = tile[cc + 0][r]; v.y = tile[cc + 1][r];
        v.z = tile[cc + 2][r]; v.w = tile[cc + 3][r];
        *(float4*)(xT + (size_t)(c0 + r) * B_TOTAL + r0 + cc) = v;
    }
}

// K2: block = 64o x 64b tile, 4 waves. Each wave does 16 o's sequentially
// (o explicitly wave-uniform -> weights/indices are SCALAR loads), lanes over
// b (xT reads + out writes coalesced; ZERO gathers, zero gather conflicts).
// Depth-first multilinear tree keeps live regs ~12; o-loop NOT unrolled
// (R4's unroll-2 + breadth-first t[32] + ww[64] spilled to scratch).
__global__ __launch_bounds__(BLOCK) void lut_main(
    const float* __restrict__ xT,
    const f2*    __restrict__ wp2,
    const int*   __restrict__ m8,
    float*       __restrict__ out)
{
    __shared__ float tile[64][65];
    const int tid  = threadIdx.x;
    const int lane = tid & 63;
    const int wv   = __builtin_amdgcn_readfirstlane(tid >> 6);   // 0..3
    const int o0   = blockIdx.x * 64;
    const int b    = blockIdx.y * 64 + lane;

    #pragma unroll 1
    for (int j16 = 0; j16 < 16; ++j16) {
        const int o = __builtin_amdgcn_readfirstlane(o0 + wv * 16 + j16);

        int m[NIN];
        const int* __restrict__ mp = m8 + o * 8;
        #pragma unroll
        for (int i = 0; i < NIN; ++i) m[i] = mp[i];              // s_load

        float xv[NIN];
        #pragma unroll
        for (int i = 0; i < NIN; ++i)
            xv[i] = xT[(size_t)m[i] * B_TOTAL + b];              // coalesced 256B

        const f2* __restrict__ wp = wp2 + (size_t)o * 32;        // s_load x4

        // depth-first multilinear tree: bit0 at leaves (precomp pair diffs)
        float a5[2];
        #pragma unroll
        for (int h5 = 0; h5 < 2; ++h5) {
            float a4[2];
            #pragma unroll
            for (int h4 = 0; h4 < 2; ++h4) {
                float a3[2];
                #pragma unroll
                for (int h3 = 0; h3 < 2; ++h3) {
                    float a2[2];
                    #pragma unroll
                    for (int h2 = 0; h2 < 2; ++h2) {
                        float a1[2];
                        #pragma unroll
                        for (int h1 = 0; h1 < 2; ++h1) {
                            int j = (((h5 * 2 + h4) * 2 + h3) * 2 + h2) * 2 + h1;
                            f2 w = wp[j];
                            a1[h1] = fmaf(xv[0], w.y, w.x);
                        }
                        a2[h2] = fmaf(xv[1], a1[1] - a1[0], a1[0]);
                    }
                    a3[h3] = fmaf(xv[2], a2[1] - a2[0], a2[0]);
                }
                a4[h4] = fmaf(xv[3], a3[1] - a3[0], a3[0]);
            }
            a5[h5] = fmaf(xv[4], a4[1] - a4[0], a4[0]);
        }
        float res = fmaf(xv[5], a5[1] - a5[0], a5[0]);

        tile[wv * 16 + j16][lane] = res;     // consecutive banks, 2-way: free
    }

    __syncthreads();
    // transposed write-out: lanes over o -> out rows coalesced
    #pragma unroll
    for (int r = 0; r < 16; ++r) {
        const int e  = r * BLOCK + tid;
        const int bl = e >> 6;               // wave-uniform
        const int ol = e & 63;               // lanes over o
        out[(size_t)(blockIdx.y * 64 + bl) * O_TOTAL + o0 + ol] = tile[ol][bl];
    }
}

extern "C" void kernel_launch(void* const* d_in, const int* in_sizes, int n_in,
                              void* d_out, int out_size, void* d_ws, size_t ws_size,
                              hipStream_t stream)
{
    const float*        x       = (const float*)d_in[0];
    const float*        table   = (const float*)d_in[1];
    const unsigned int* map_raw = (const unsigned int*)d_in[2];
    float* out = (float*)d_out;
    f2*    wp2 = (f2*) ((char*)d_ws + WS_WP2);
    int*   m8  = (int*)((char*)d_ws + WS_M8);
    float* xT  = (float*)((char*)d_ws + WS_XT);

    xpose_prep<<<dim3(32, 32), BLOCK, 0, stream>>>(x, table, map_raw, xT, wp2, m8);
    lut_main<<<dim3(32, 32), BLOCK, 0, stream>>>(xT, wp2, m8, out);
}